// Round 8
// baseline (1117.702 us; speedup 1.0000x reference)
//
#include <hip/hip_runtime.h>
#include <stdint.h>

typedef __bf16 bf16;
typedef __bf16 bf16x4 __attribute__((ext_vector_type(4)));
typedef __bf16 bf16x8 __attribute__((ext_vector_type(8)));
typedef float f32x4 __attribute__((ext_vector_type(4)));

#define GLD_LDS16(g, l)                                                        \
  __builtin_amdgcn_global_load_lds(                                            \
      (const __attribute__((address_space(1))) void*)(g),                      \
      (__attribute__((address_space(3))) void*)(l), 16, 0, 0)

#define BAR() asm volatile("s_barrier" ::: "memory")
#define VMW(n) asm volatile("s_waitcnt vmcnt(" #n ")" ::: "memory")
#define PRIO(x) __builtin_amdgcn_s_setprio(x)

// ---------------------------------------------------------------- fused pre-work:
// blocks [0,4096): buildW (one output column j each)
// blocks [4096,5120): cast x fp32->bf16 + ||x||^2 partials
__global__ __launch_bounds__(256) void k_pre(
    const float* __restrict__ x, const float* __restrict__ c0,
    const float* __restrict__ c1, const float* __restrict__ c2,
    bf16* __restrict__ Wt, bf16* __restrict__ xb, float* __restrict__ pbuf) {
  const int b = blockIdx.x;
  if (b < 4096) {
    const int j = b;
    const int j0 = j >> 8, j1 = (j >> 4) & 15, j2 = j & 15;
    const int t = threadIdx.x;
    const int i0 = t >> 4, i1 = t & 15;
    float t0[8];
    {
      float4 v0 = *(const float4*)&c0[(i0 * 16 + j0) * 8];
      float4 v1 = *(const float4*)&c0[(i0 * 16 + j0) * 8 + 4];
      t0[0] = v0.x; t0[1] = v0.y; t0[2] = v0.z; t0[3] = v0.w;
      t0[4] = v1.x; t0[5] = v1.y; t0[6] = v1.z; t0[7] = v1.w;
    }
    float a[8];
#pragma unroll
    for (int r2 = 0; r2 < 8; ++r2) a[r2] = 0.f;
#pragma unroll
    for (int r1 = 0; r1 < 8; ++r1) {
      const float* row = &c1[((r1 * 16 + i1) * 16 + j1) * 8];
      float4 u0 = *(const float4*)row;
      float4 u1 = *(const float4*)(row + 4);
      a[0] += t0[r1] * u0.x; a[1] += t0[r1] * u0.y;
      a[2] += t0[r1] * u0.z; a[3] += t0[r1] * u0.w;
      a[4] += t0[r1] * u1.x; a[5] += t0[r1] * u1.y;
      a[6] += t0[r1] * u1.z; a[7] += t0[r1] * u1.w;
    }
    union { bf16 h[16]; bf16x8 v[2]; } u;
#pragma unroll
    for (int i2 = 0; i2 < 16; ++i2) {
      float s = 0.f;
#pragma unroll
      for (int r2 = 0; r2 < 8; ++r2) s += a[r2] * c2[(r2 * 16 + i2) * 16 + j2];
      u.h[i2] = (bf16)s;
    }
    bf16* dst = Wt + (size_t)j * 4096 + i0 * 256 + i1 * 16;
    ((bf16x8*)dst)[0] = u.v[0];
    ((bf16x8*)dst)[1] = u.v[1];
  } else {
    const int n4 = 8192 * 4096 / 4;
    int tid = (b - 4096) * 256 + threadIdx.x;
    const int stride = 1024 * 256;
    const float4* x4 = (const float4*)x;
    bf16x4* xb4 = (bf16x4*)xb;
    float acc = 0.f;
    for (int i = tid; i < n4; i += stride) {
      float4 v = x4[i];
      acc += v.x * v.x + v.y * v.y + v.z * v.z + v.w * v.w;
      bf16x4 bb;
      bb.x = (bf16)v.x; bb.y = (bf16)v.y; bb.z = (bf16)v.z; bb.w = (bf16)v.w;
      xb4[i] = bb;
    }
#pragma unroll
    for (int off = 32; off; off >>= 1) acc += __shfl_down(acc, off);
    __shared__ float red[4];
    if ((threadIdx.x & 63) == 0) red[threadIdx.x >> 6] = acc;
    __syncthreads();
    if (threadIdx.x == 0) pbuf[b - 4096] = red[0] + red[1] + red[2] + red[3];
  }
}

// ---------------------------------------------------------------- dense G from TT cores, all in-block
__global__ __launch_bounds__(256) void k_buildG(const float* __restrict__ c0,
                                                const float* __restrict__ c1,
                                                const float* __restrict__ c2,
                                                bf16* __restrict__ G,
                                                const float* __restrict__ pbuf,
                                                float* __restrict__ scal) {
  __shared__ float s_g2[16384];   // 64KB: g2[p2][jj2]
  __shared__ float s_g0m[16384];  // 64KB: c1 staging -> g0t[p1][jj0] -> m_t[p2][jj0]
  __shared__ float s_cc[4096];    // 16KB: c0|c2 -> g1slice
  const int t = threadIdx.x;
  const int j1 = blockIdx.x >> 4, j1p = blockIdx.x & 15;

  if (blockIdx.x == 0) {
    float a = pbuf[t * 4] + pbuf[t * 4 + 1] + pbuf[t * 4 + 2] + pbuf[t * 4 + 3];
#pragma unroll
    for (int off = 32; off; off >>= 1) a += __shfl_down(a, off);
    if ((t & 63) == 0) s_g2[t >> 6] = a;
    __syncthreads();
    if (t == 0) {
      scal[0] = s_g2[0] + s_g2[1] + s_g2[2] + s_g2[3];
      scal[1] = 0.f; scal[2] = 0.f;
    }
    __syncthreads();
  }

  {
    const float4* c0f = (const float4*)c0;
    const float4* c2f = (const float4*)c2;
    const float4* c1f = (const float4*)c1;
    float4* cc = (float4*)s_cc;
    float4* cm = (float4*)s_g0m;
    for (int k = t; k < 512; k += 256) cc[k] = c0f[k];
    for (int k = t; k < 512; k += 256) cc[512 + k] = c2f[k];
    for (int k = t; k < 4096; k += 256) cm[k] = c1f[k];
  }
  __syncthreads();

  {
    float accg[64];
#pragma unroll
    for (int i = 0; i < 64; ++i) accg[i] = 0.f;
    const int j2 = t >> 4, j2p = t & 15;
    const float* c2L = s_cc + 2048;
#pragma unroll 1
    for (int i2 = 0; i2 < 16; ++i2) {
      float a2[8], b2[8];
#pragma unroll
      for (int r = 0; r < 8; ++r) {
        a2[r] = c2L[(r * 16 + i2) * 16 + j2];
        b2[r] = c2L[(r * 16 + i2) * 16 + j2p];
      }
#pragma unroll
      for (int p2 = 0; p2 < 64; ++p2) accg[p2] += a2[p2 >> 3] * b2[p2 & 7];
    }
#pragma unroll
    for (int p2 = 0; p2 < 64; ++p2) s_g2[p2 * 256 + t] = accg[p2];
  }

  float g0acc[64];
  {
#pragma unroll
    for (int i = 0; i < 64; ++i) g0acc[i] = 0.f;
    const int j0 = t >> 4, j0p = t & 15;
#pragma unroll 1
    for (int i0 = 0; i0 < 16; ++i0) {
      float a0[8], b0[8];
#pragma unroll
      for (int r = 0; r < 8; ++r) {
        a0[r] = s_cc[(i0 * 16 + j0) * 8 + r];
        b0[r] = s_cc[(i0 * 16 + j0p) * 8 + r];
      }
#pragma unroll
      for (int p1 = 0; p1 < 64; ++p1) g0acc[p1] += a0[p1 >> 3] * b0[p1 & 7];
    }
  }
  float g1acc[16];
  {
#pragma unroll
    for (int i = 0; i < 16; ++i) g1acc[i] = 0.f;
    const int p1 = t >> 2, r1 = p1 >> 3, r1p = p1 & 7;
#pragma unroll 1
    for (int i1 = 0; i1 < 16; ++i1) {
      float a1[8], b1[8];
#pragma unroll
      for (int r = 0; r < 8; ++r) {
        a1[r] = s_g0m[((r1 * 16 + i1) * 16 + j1) * 8 + r];
        b1[r] = s_g0m[((r1p * 16 + i1) * 16 + j1p) * 8 + r];
      }
#pragma unroll
      for (int v = 0; v < 16; ++v) {
        int p2 = (t & 3) * 16 + v;
        g1acc[v] += a1[p2 >> 3] * b1[p2 & 7];
      }
    }
  }
  __syncthreads();
#pragma unroll
  for (int p1 = 0; p1 < 64; ++p1) s_g0m[p1 * 256 + t] = g0acc[p1];
#pragma unroll
  for (int v = 0; v < 16; ++v) s_cc[(t >> 2) * 64 + (t & 3) * 16 + v] = g1acc[v];
  __syncthreads();

  float m[64];
#pragma unroll
  for (int i = 0; i < 64; ++i) m[i] = 0.f;
#pragma unroll 4
  for (int p1 = 0; p1 < 64; ++p1) {
    float av = s_g0m[p1 * 256 + t];
#pragma unroll
    for (int q = 0; q < 16; ++q) {
      float4 v = ((const float4*)s_cc)[p1 * 16 + q];
      m[q * 4 + 0] += av * v.x; m[q * 4 + 1] += av * v.y;
      m[q * 4 + 2] += av * v.z; m[q * 4 + 3] += av * v.w;
    }
  }
  __syncthreads();
#pragma unroll
  for (int p2 = 0; p2 < 64; ++p2) s_g0m[p2 * 256 + t] = m[p2];
  __syncthreads();

  const int bcol = (t & 15) * 16;
  const int j2 = t & 15;
#pragma unroll 1
  for (int rep = 0; rep < 2; ++rep) {
    const int r0 = (((t >> 4) + rep * 16)) * 8;
    float acc2[8][16];
#pragma unroll
    for (int i = 0; i < 8; ++i)
#pragma unroll
      for (int c = 0; c < 16; ++c) acc2[i][c] = 0.f;
#pragma unroll 2
    for (int p2 = 0; p2 < 64; ++p2) {
      float4 mv0 = *(const float4*)&s_g0m[p2 * 256 + r0];
      float4 mv1 = *(const float4*)&s_g0m[p2 * 256 + r0 + 4];
      float mv[8] = {mv0.x, mv0.y, mv0.z, mv0.w, mv1.x, mv1.y, mv1.z, mv1.w};
      float gv[16];
#pragma unroll
      for (int q = 0; q < 4; ++q) {
        float4 v = *(const float4*)&s_g2[p2 * 256 + bcol + q * 4];
        gv[q * 4 + 0] = v.x; gv[q * 4 + 1] = v.y;
        gv[q * 4 + 2] = v.z; gv[q * 4 + 3] = v.w;
      }
#pragma unroll
      for (int i = 0; i < 8; ++i)
#pragma unroll
        for (int c = 0; c < 16; ++c) acc2[i][c] += mv[i] * gv[c];
    }
#pragma unroll
    for (int i = 0; i < 8; ++i) {
      const int jj0 = r0 + i;
      const int j0 = jj0 >> 4, j0p = jj0 & 15;
      bf16* d = G + (size_t)(j0 * 256 + j1 * 16 + j2) * 4096 + (j0p * 256 + j1p * 16);
      union { bf16 h[16]; bf16x8 v[2]; } u;
#pragma unroll
      for (int c = 0; c < 16; ++c) u.h[c] = (bf16)acc2[i][c];
      ((bf16x8*)d)[0] = u.v[0];
      ((bf16x8*)d)[1] = u.v[1];
    }
  }
}

// ---------------------------------------------------------------- 128x256 BT-form GEMM core, 2 blocks/CU
// C[m,n] = sum_k A[m,k]*Bt[n,k].  BM=128, BN=256, BK=32, 256 thr = 4 waves (2M x 2N).
// KEY CHANGE vs 256^2/1-block: LDS = 3 x 24KB triple buffer = 72KB -> TWO independent
// blocks co-resident per CU (8 waves total, separate barrier domains).  One block's
// LDS-read window overlaps the other's MFMA window (m114 co-scheduling) -- breaking the
// CU-wide read/MFMA convoy that held MfmaUtil at ~49% with 1 block/CU.
// Triple buffer -> ONE barrier per K-tile: stage target buf[(T+2)%3] was last read at
// tile T-1, whose readers crossed the end-of-(T-1) barrier.  vmcnt(6) publish (6 loads
// per tile: A=2, B=4 instruction-slots of 4KB/block).
// Swizzle: 32-col rows, slot s of row r holds chunk s ^ ((r>>1)&3)  (2-way = free).
#define STAGE(kt, b)                                                                   \
  do {                                                                                 \
    GLD_LDS16(srcA + (size_t)(kt) * 32, smem + (b) * 24576 + wofs);                    \
    GLD_LDS16(srcA + (size_t)64 * K + (kt) * 32, smem + (b) * 24576 + 4096 + wofs);    \
    GLD_LDS16(srcB + (size_t)(kt) * 32, smem + (b) * 24576 + 8192 + wofs);             \
    GLD_LDS16(srcB + (size_t)64 * K + (kt) * 32,                                       \
              smem + (b) * 24576 + 12288 + wofs);                                      \
    GLD_LDS16(srcB + (size_t)128 * K + (kt) * 32,                                      \
              smem + (b) * 24576 + 16384 + wofs);                                      \
    GLD_LDS16(srcB + (size_t)192 * K + (kt) * 32,                                      \
              smem + (b) * 24576 + 20480 + wofs);                                      \
  } while (0)
#define LDF(b)                                                                         \
  do {                                                                                 \
    const char* As_ = smem + (b) * 24576;                                              \
    const char* Bs_ = smem + (b) * 24576 + 8192;                                       \
    _Pragma("unroll") for (int mi_ = 0; mi_ < 4; ++mi_)                                \
        af[mi_] = *(const bf16x8*)(As_ + (wm * 64 + mi_ * 16 + lr) * 64 + cb);         \
    _Pragma("unroll") for (int ni_ = 0; ni_ < 8; ++ni_)                                \
        bfr[ni_] = *(const bf16x8*)(Bs_ + (wn * 128 + ni_ * 16 + lr) * 64 + cb);       \
  } while (0)
#define MQ_ALL()                                                                       \
  do {                                                                                 \
    PRIO(1);                                                                           \
    _Pragma("unroll") for (int mi_ = 0; mi_ < 4; ++mi_)                                \
    _Pragma("unroll") for (int ni_ = 0; ni_ < 8; ++ni_)                                \
        acc[mi_][ni_] = __builtin_amdgcn_mfma_f32_16x16x32_bf16(                       \
            af[mi_], bfr[ni_], acc[mi_][ni_], 0, 0, 0);                                \
    PRIO(0);                                                                           \
  } while (0)

__device__ __forceinline__ void run_core(const bf16* __restrict__ Ag,
                                         const bf16* __restrict__ Bg, const int K,
                                         const int bx, const int by, char* smem,
                                         f32x4 (&acc)[4][8]) {
  const int t = threadIdx.x;
  const int w = t >> 6, lane = t & 63;
  const int q = lane >> 4, lr = lane & 15;
  const int wm = w & 1, wn = w >> 1;

  const int r0 = t >> 2;  // 0..63
  const int colc = ((t & 3) ^ ((r0 >> 1) & 3)) * 8;
  const bf16* srcA = Ag + (size_t)(by * 128 + r0) * K + colc;
  const bf16* srcB = Bg + (size_t)(bx * 256 + r0) * K + colc;
  const int wofs = w << 10;

  const int cb = (q ^ ((lr >> 1) & 3)) << 4;

#pragma unroll
  for (int i = 0; i < 4; ++i)
#pragma unroll
    for (int j = 0; j < 8; ++j) acc[i][j] = (f32x4){0.f, 0.f, 0.f, 0.f};

  bf16x8 af[4];
  bf16x8 bfr[8];

  // prologue: tiles 0 (buf0), 1 (buf1); vmcnt(6) -> tile0 landed, tile1 in flight
  STAGE(0, 0);
  STAGE(1, 1);
  VMW(6);
  BAR();

  const int NT = K >> 5;  // 128 K-tiles; loop unrolled x3 for static buf indices
#pragma unroll 1
  for (int tt = 0; tt < NT - 2; tt += 3) {
    // tile tt (buf0): stage tt+2 -> buf2 (last read at tile tt-1, pre-prev barrier)
    STAGE(tt + 2, 2);
    LDF(0);
    MQ_ALL();
    VMW(6);  // publish tile tt+1
    BAR();
    // tile tt+1 (buf1): stage tt+3 -> buf0
    STAGE(tt + 3, 0);
    LDF(1);
    MQ_ALL();
    VMW(6);  // publish tile tt+2
    BAR();
    // tile tt+2 (buf2): stage tt+4 -> buf1
    STAGE(tt + 4, 1);
    LDF(2);
    MQ_ALL();
    VMW(6);  // publish tile tt+3
    BAR();
  }
  // NT = 128 = 3*42 + 2: loop covers tiles 0..125 (stages through tile 127).
  // peel tile 126 (buf0): no stage left
  LDF(0);
  MQ_ALL();
  VMW(0);  // tile 127 fully landed
  BAR();
  // peel tile 127 (buf1)
  LDF(1);
  MQ_ALL();
}

// ---------------------------------------------------------------- GEMM epilogue kernels
// MODE 0: xl0 = A@Wt^T + bias + gate0 ; bf_out ; ssq_out                 [A = xbf]
// MODE 2: xl1 = 2*xl0 - A@G + (gate1-gate0) ; bf_out ; ssq_out          [A = xl0]
// MODE 3: out = xl_prev - A@G + xl0 + (gate2-gate0)  (fp32)             [A = xl1]
template <int MODE>
__global__ __launch_bounds__(256, 2) void k_gemm(
    const bf16* __restrict__ A, const bf16* __restrict__ Bt, int M, int N, int K,
    const float* __restrict__ bias, const bf16* __restrict__ xl0,
    const bf16* __restrict__ xl_prev, float* f32_out, bf16* __restrict__ bf_out,
    const float* __restrict__ ssq_a, const float* __restrict__ ssq_b,
    float* __restrict__ ssq_out) {
  const int nb = gridDim.x * gridDim.y;  // 1024 (%8==0)
  const int lin = blockIdx.y * gridDim.x + blockIdx.x;
  const int sw = (lin & 7) * (nb >> 3) + (lin >> 3);
  const int bx = sw % gridDim.x, by = sw / gridDim.x;
  __shared__ char smem[73728];  // 3 x 24KB

  float gate = 0.f;
  if constexpr (MODE == 0) {
    gate = (*ssq_a > 1.0f) ? 0.f : -1.f;
  } else {
    float g0v = (*ssq_a > 1.0f) ? 0.f : -1.f;
    float gtv = (*ssq_b > 1.0f) ? 0.f : -1.f;
    gate = gtv - g0v;
  }
  VMW(0);  // drain gate loads so manual vmcnt counts stay exact

  f32x4 acc[4][8];
  run_core(A, Bt, K, bx, by, smem, acc);

  const int t = threadIdx.x;
  const int w = t >> 6, lane = t & 63;
  const int q = lane >> 4, lr = lane & 15;
  const int wm = w & 1, wn = w >> 1;
  float ssql = 0.f;
#pragma unroll
  for (int mi = 0; mi < 4; ++mi) {
    const int grow = by * 128 + wm * 64 + mi * 16 + q * 4;
#pragma unroll
    for (int r = 0; r < 4; ++r) {
      const size_t rowb = (size_t)(grow + r) * N;
#pragma unroll
      for (int ni = 0; ni < 8; ++ni) {
        const int gcol = bx * 256 + wn * 128 + ni * 16 + lr;
        const size_t idx = rowb + gcol;
        float v = acc[mi][ni][r];
        if constexpr (MODE == 0) {
          float xl = v + bias[gcol] + gate;
          bf_out[idx] = (bf16)xl;
          ssql += xl * xl;
        } else if constexpr (MODE == 2) {
          float xl = 2.0f * (float)xl0[idx] - v + gate;
          bf_out[idx] = (bf16)xl;
          ssql += xl * xl;
        } else {
          f32_out[idx] = (float)xl_prev[idx] - v + (float)xl0[idx] + gate;
        }
      }
    }
  }
  if constexpr (MODE == 0 || MODE == 2) {
#pragma unroll
    for (int off = 32; off; off >>= 1) ssql += __shfl_down(ssql, off);
    __syncthreads();  // pipeline drained; reuse smem for reduction
    float* red = (float*)smem;
    if (lane == 0) red[w] = ssql;
    __syncthreads();
    if (t == 0) atomicAdd(ssq_out, red[0] + red[1] + red[2] + red[3]);
  }
}

// ----------------------------------------------------------------
extern "C" void kernel_launch(void* const* d_in, const int* in_sizes, int n_in,
                              void* d_out, int out_size, void* d_ws, size_t ws_size,
                              hipStream_t stream) {
  const float* x = (const float*)d_in[0];
  const float* c0 = (const float*)d_in[1];
  const float* c1 = (const float*)d_in[2];
  const float* c2 = (const float*)d_in[3];
  const float* bias = (const float*)d_in[4];
  float* out = (float*)d_out;

  const int B = 8192, F = 4096;
  char* ws = (char*)d_ws;
  float* scal = (float*)ws;                              // [0]=ssq_x [1]=ssq_xl0 [2]=ssq_xl1
  bf16* xbf = (bf16*)(ws + 256);                         // 64 MiB (x bf16; reused as xl1)
  bf16* Wt = (bf16*)(ws + 256 + (size_t)67108864);       // 32 MiB
  bf16* G = (bf16*)(ws + 256 + (size_t)100663296);       // 32 MiB
  bf16* xl0 = (bf16*)(ws + 256 + (size_t)134217728);     // 64 MiB
  bf16* xl1 = xbf;  // xbf dead after mv GEMM
  float* pbuf = (float*)xl0;  // 4 KB cast partials (xl0 region not yet written)

  // fused pre-work: buildW (4096) | cast+ssq partials (1024)
  k_pre<<<5120, 256, 0, stream>>>(x, c0, c1, c2, Wt, xbf, pbuf);
  // dense G = W^T W fully in-block from TT cores; block 0 finalizes scal[0..2]
  k_buildG<<<256, 256, 0, stream>>>(c0, c1, c2, G, pbuf, scal);

  dim3 g1d(F / 256, B / 128);  // 16 x 64 = 1024 blocks
  // xl0 = x@W + bias + gate0
  k_gemm<0><<<g1d, 256, 0, stream>>>(xbf, Wt, B, F, F, bias, nullptr, nullptr,
                                     nullptr, xl0, &scal[0], nullptr, &scal[1]);
  // xl1 = 2*xl0 - xl0@G + (gate1-gate0)
  k_gemm<2><<<g1d, 256, 0, stream>>>(xl0, G, B, F, F, nullptr, xl0, nullptr,
                                     nullptr, xl1, &scal[0], &scal[1], &scal[2]);
  // out = xl1 - xl1@G + xl0 + (gate2-gate0)
  k_gemm<3><<<g1d, 256, 0, stream>>>(xl1, G, B, F, F, nullptr, xl0, xl1,
                                     out, nullptr, &scal[0], &scal[2], nullptr);
}

// Round 9
// 1037.082 us; speedup vs baseline: 1.0777x; 1.0777x over previous
//
#include <hip/hip_runtime.h>
#include <stdint.h>

typedef __bf16 bf16;
typedef __bf16 bf16x4 __attribute__((ext_vector_type(4)));
typedef __bf16 bf16x8 __attribute__((ext_vector_type(8)));
typedef float f32x4 __attribute__((ext_vector_type(4)));

#define GLD_LDS16(g, l)                                                        \
  __builtin_amdgcn_global_load_lds(                                            \
      (const __attribute__((address_space(1))) void*)(g),                      \
      (__attribute__((address_space(3))) void*)(l), 16, 0, 0)

#define BAR() asm volatile("s_barrier" ::: "memory")
#define VMW(n) asm volatile("s_waitcnt vmcnt(" #n ")" ::: "memory")
#define PRIO(x) __builtin_amdgcn_s_setprio(x)

// ---------------------------------------------------------------- fused pre-work:
// blocks [0,4096): buildW (one output column j each)
// blocks [4096,5120): cast x fp32->bf16 + ||x||^2 partials
__global__ __launch_bounds__(256) void k_pre(
    const float* __restrict__ x, const float* __restrict__ c0,
    const float* __restrict__ c1, const float* __restrict__ c2,
    bf16* __restrict__ Wt, bf16* __restrict__ xb, float* __restrict__ pbuf) {
  const int b = blockIdx.x;
  if (b < 4096) {
    const int j = b;
    const int j0 = j >> 8, j1 = (j >> 4) & 15, j2 = j & 15;
    const int t = threadIdx.x;
    const int i0 = t >> 4, i1 = t & 15;
    float t0[8];
    {
      float4 v0 = *(const float4*)&c0[(i0 * 16 + j0) * 8];
      float4 v1 = *(const float4*)&c0[(i0 * 16 + j0) * 8 + 4];
      t0[0] = v0.x; t0[1] = v0.y; t0[2] = v0.z; t0[3] = v0.w;
      t0[4] = v1.x; t0[5] = v1.y; t0[6] = v1.z; t0[7] = v1.w;
    }
    float a[8];
#pragma unroll
    for (int r2 = 0; r2 < 8; ++r2) a[r2] = 0.f;
#pragma unroll
    for (int r1 = 0; r1 < 8; ++r1) {
      const float* row = &c1[((r1 * 16 + i1) * 16 + j1) * 8];
      float4 u0 = *(const float4*)row;
      float4 u1 = *(const float4*)(row + 4);
      a[0] += t0[r1] * u0.x; a[1] += t0[r1] * u0.y;
      a[2] += t0[r1] * u0.z; a[3] += t0[r1] * u0.w;
      a[4] += t0[r1] * u1.x; a[5] += t0[r1] * u1.y;
      a[6] += t0[r1] * u1.z; a[7] += t0[r1] * u1.w;
    }
    union { bf16 h[16]; bf16x8 v[2]; } u;
#pragma unroll
    for (int i2 = 0; i2 < 16; ++i2) {
      float s = 0.f;
#pragma unroll
      for (int r2 = 0; r2 < 8; ++r2) s += a[r2] * c2[(r2 * 16 + i2) * 16 + j2];
      u.h[i2] = (bf16)s;
    }
    bf16* dst = Wt + (size_t)j * 4096 + i0 * 256 + i1 * 16;
    ((bf16x8*)dst)[0] = u.v[0];
    ((bf16x8*)dst)[1] = u.v[1];
  } else {
    const int n4 = 8192 * 4096 / 4;
    int tid = (b - 4096) * 256 + threadIdx.x;
    const int stride = 1024 * 256;
    const float4* x4 = (const float4*)x;
    bf16x4* xb4 = (bf16x4*)xb;
    float acc = 0.f;
    for (int i = tid; i < n4; i += stride) {
      float4 v = x4[i];
      acc += v.x * v.x + v.y * v.y + v.z * v.z + v.w * v.w;
      bf16x4 bb;
      bb.x = (bf16)v.x; bb.y = (bf16)v.y; bb.z = (bf16)v.z; bb.w = (bf16)v.w;
      xb4[i] = bb;
    }
#pragma unroll
    for (int off = 32; off; off >>= 1) acc += __shfl_down(acc, off);
    __shared__ float red[4];
    if ((threadIdx.x & 63) == 0) red[threadIdx.x >> 6] = acc;
    __syncthreads();
    if (threadIdx.x == 0) pbuf[b - 4096] = red[0] + red[1] + red[2] + red[3];
  }
}

// ---------------------------------------------------------------- dense G from TT cores, in-block
// block = (j1,j1').  Conflict-free rewrite: thread t owns jj0 = t, so stage-1's m[64]
// lives entirely in registers (no m_t LDS round-trip, no g0t round-trip).  Stage-2 reads
// g2 rows with ALL lanes at the same address (pure LDS broadcast, 0 conflicts) -- the old
// layout's gv reads were an 8-way bank conflict (~25us).  g2 overlays the dead c1 staging
// region: LDS 144KB -> 80KB.  Block 0 finalizes scal[0..2] from cast partials.
__global__ __launch_bounds__(256) void k_buildG(const float* __restrict__ c0,
                                                const float* __restrict__ c1,
                                                const float* __restrict__ c2,
                                                bf16* __restrict__ G,
                                                const float* __restrict__ pbuf,
                                                float* __restrict__ scal) {
  __shared__ float s_c1g2[16384];  // 64KB: c1 staging -> g2[p2][jj2]
  __shared__ float s_cc[4096];     // 16KB: c0[0:2048]|c2[2048:4096] -> g1slice[p1][p2]
  __shared__ float red2[4];
  const int t = threadIdx.x;
  const int j1 = blockIdx.x >> 4, j1p = blockIdx.x & 15;

  if (blockIdx.x == 0) {  // ssq finalize
    float a = pbuf[t * 4] + pbuf[t * 4 + 1] + pbuf[t * 4 + 2] + pbuf[t * 4 + 3];
#pragma unroll
    for (int off = 32; off; off >>= 1) a += __shfl_down(a, off);
    if ((t & 63) == 0) red2[t >> 6] = a;
    __syncthreads();
    if (t == 0) {
      scal[0] = red2[0] + red2[1] + red2[2] + red2[3];
      scal[1] = 0.f; scal[2] = 0.f;
    }
    __syncthreads();
  }

  // stage cores: c0 -> s_cc[0:2048], c2 -> s_cc[2048:4096], c1 -> s_c1g2
  {
    const float4* c0f = (const float4*)c0;
    const float4* c2f = (const float4*)c2;
    const float4* c1f = (const float4*)c1;
    float4* cc = (float4*)s_cc;
    float4* cm = (float4*)s_c1g2;
    for (int k = t; k < 512; k += 256) cc[k] = c0f[k];
    for (int k = t; k < 512; k += 256) cc[512 + k] = c2f[k];
    for (int k = t; k < 4096; k += 256) cm[k] = c1f[k];
  }
  __syncthreads();

  // --- all-register Gram computes (pure reads of staged cores) ---
  // g2 slice for jj2 = t:  accg[p2] = sum_i2 c2[r2,i2,j2] c2[r2',i2,j2']
  float accg[64];
  {
#pragma unroll
    for (int i = 0; i < 64; ++i) accg[i] = 0.f;
    const int j2 = t >> 4, j2p = t & 15;
    const float* c2L = s_cc + 2048;
#pragma unroll 1
    for (int i2 = 0; i2 < 16; ++i2) {
      float a2[8], b2[8];
#pragma unroll
      for (int r = 0; r < 8; ++r) {
        a2[r] = c2L[(r * 16 + i2) * 16 + j2];
        b2[r] = c2L[(r * 16 + i2) * 16 + j2p];
      }
#pragma unroll
      for (int p2 = 0; p2 < 64; ++p2) accg[p2] += a2[p2 >> 3] * b2[p2 & 7];
    }
  }
  // g0 row for jj0 = t: g0acc[p1] = sum_i0 c0[i0,j0,r1] c0[i0,j0',r1']
  float g0acc[64];
  {
#pragma unroll
    for (int i = 0; i < 64; ++i) g0acc[i] = 0.f;
    const int j0 = t >> 4, j0p = t & 15;
#pragma unroll 1
    for (int i0 = 0; i0 < 16; ++i0) {
      float a0[8], b0[8];
#pragma unroll
      for (int r = 0; r < 8; ++r) {
        a0[r] = s_cc[(i0 * 16 + j0) * 8 + r];
        b0[r] = s_cc[(i0 * 16 + j0p) * 8 + r];
      }
#pragma unroll
      for (int p1 = 0; p1 < 64; ++p1) g0acc[p1] += a0[p1 >> 3] * b0[p1 & 7];
    }
  }
  // g1 slice: thread t -> p1 = t>>2, p2 = (t&3)*16 + v
  float g1acc[16];
  {
#pragma unroll
    for (int i = 0; i < 16; ++i) g1acc[i] = 0.f;
    const int p1 = t >> 2, r1 = p1 >> 3, r1p = p1 & 7;
#pragma unroll 1
    for (int i1 = 0; i1 < 16; ++i1) {
      float a1[8], b1[8];
#pragma unroll
      for (int r = 0; r < 8; ++r) {
        a1[r] = s_c1g2[((r1 * 16 + i1) * 16 + j1) * 8 + r];
        b1[r] = s_c1g2[((r1p * 16 + i1) * 16 + j1p) * 8 + r];
      }
#pragma unroll
      for (int v = 0; v < 16; ++v) {
        int p2 = (t & 3) * 16 + v;
        g1acc[v] += a1[p2 >> 3] * b1[p2 & 7];
      }
    }
  }
  __syncthreads();  // all staged-core reads retired -> safe to overwrite
#pragma unroll
  for (int p2 = 0; p2 < 64; ++p2) s_c1g2[p2 * 256 + t] = accg[p2];  // g2[p2][jj2]
#pragma unroll
  for (int v = 0; v < 16; ++v) s_cc[(t >> 2) * 64 + (t & 3) * 16 + v] = g1acc[v];
  __syncthreads();

  // stage 1 (in-register): m[p2] = sum_p1 g0acc[p1] * g1[p1][p2]   (g1 reads broadcast)
  float m[64];
#pragma unroll
  for (int i = 0; i < 64; ++i) m[i] = 0.f;
#pragma unroll 4
  for (int p1 = 0; p1 < 64; ++p1) {
    float av = g0acc[p1];
#pragma unroll
    for (int q = 0; q < 16; ++q) {
      float4 v = ((const float4*)s_cc)[p1 * 16 + q];
      m[q * 4 + 0] += av * v.x; m[q * 4 + 1] += av * v.y;
      m[q * 4 + 2] += av * v.z; m[q * 4 + 3] += av * v.w;
    }
  }

  // stage 2: out[jj2] = sum_p2 m[p2] * g2[p2][jj2]; g2 reads are lane-uniform (broadcast).
  const int j0 = t >> 4, j0p = t & 15;
#pragma unroll 1
  for (int ch = 0; ch < 4; ++ch) {
    float o[64];
#pragma unroll
    for (int i = 0; i < 64; ++i) o[i] = 0.f;
#pragma unroll 2
    for (int p2 = 0; p2 < 64; ++p2) {
      const float4* g2r = (const float4*)&s_c1g2[p2 * 256 + ch * 64];
      const float mp = m[p2];
#pragma unroll
      for (int q = 0; q < 16; ++q) {
        float4 v = g2r[q];
        o[q * 4 + 0] += mp * v.x; o[q * 4 + 1] += mp * v.y;
        o[q * 4 + 2] += mp * v.z; o[q * 4 + 3] += mp * v.w;
      }
    }
    // jj2 = ch*64 + u: j2 = ch*4 + (u>>4), j2' = u&15
#pragma unroll
    for (int r = 0; r < 4; ++r) {
      const int row = j0 * 256 + j1 * 16 + ch * 4 + r;
      bf16* d = G + (size_t)row * 4096 + j0p * 256 + j1p * 16;
      union { bf16 h[16]; bf16x8 v[2]; } u;
#pragma unroll
      for (int c = 0; c < 16; ++c) u.h[c] = (bf16)o[r * 16 + c];
      ((bf16x8*)d)[0] = u.v[0];
      ((bf16x8*)d)[1] = u.v[1];
    }
  }
}

// ---------------------------------------------------------------- 256x256 BT-form GEMM core
// (verified R7 core: 253us, 0 bank conflicts)
// C[m,n] = sum_k A[m,k]*Bt[n,k].  BM=BN=256, BK=64, 512 thr = 8 waves (2M x 4N).
// 2 barriers per K-tile (mid + end); compiler-counted lgkmcnt paces each wave's
// reads->MFMA. vmcnt(6) publish keeps next tile's loads in flight, never drains.
// LDS chunk swizzle: slot (row,c) holds global chunk c ^ (row&7) (pre-swizzled source).
#define STAGE_A(h, kt, b)                                                              \
  do {                                                                                 \
    GLD_LDS16(srcA + (size_t)((h) * 128) * K + (kt) * 64,                              \
              smem + (b) * 65536 + (h) * 16384 + wofs);                                \
    GLD_LDS16(srcA + (size_t)((h) * 128 + 64) * K + (kt) * 64,                         \
              smem + (b) * 65536 + (h) * 16384 + 8192 + wofs);                         \
  } while (0)
#define STAGE_B(h, kt, b)                                                              \
  do {                                                                                 \
    GLD_LDS16(srcB + (size_t)((h) * 128) * K + (kt) * 64,                              \
              smem + (b) * 65536 + 32768 + (h) * 16384 + wofs);                        \
    GLD_LDS16(srcB + (size_t)((h) * 128 + 64) * K + (kt) * 64,                         \
              smem + (b) * 65536 + 32768 + (h) * 16384 + 8192 + wofs);                 \
  } while (0)
#define LDA(ms, b)                                                                     \
  do {                                                                                 \
    const char* s_ = smem + (b) * 65536 + (ms) * 16384 + aRow;                         \
    _Pragma("unroll") for (int mi_ = 0; mi_ < 4; ++mi_) {                              \
      af[mi_][0] = *(const bf16x8*)(s_ + mi_ * 2048 + cb0);                            \
      af[mi_][1] = *(const bf16x8*)(s_ + mi_ * 2048 + cb1);                            \
    }                                                                                  \
  } while (0)
#define LDB(ns, b)                                                                     \
  do {                                                                                 \
    const char* s_ = smem + (b) * 65536 + 32768 + (ns) * 16384 + bRow;                 \
    _Pragma("unroll") for (int ni_ = 0; ni_ < 2; ++ni_) {                              \
      bfr[ns][ni_][0] = *(const bf16x8*)(s_ + ni_ * 2048 + cb0);                       \
      bfr[ns][ni_][1] = *(const bf16x8*)(s_ + ni_ * 2048 + cb1);                       \
    }                                                                                  \
  } while (0)
#define MQ(ms, ns)                                                                     \
  do {                                                                                 \
    PRIO(1);                                                                           \
    _Pragma("unroll") for (int mi_ = 0; mi_ < 4; ++mi_)                                \
    _Pragma("unroll") for (int ni_ = 0; ni_ < 2; ++ni_)                                \
    _Pragma("unroll") for (int ks_ = 0; ks_ < 2; ++ks_)                                \
        acc[(ms) * 4 + mi_][(ns) * 2 + ni_] =                                          \
            __builtin_amdgcn_mfma_f32_16x16x32_bf16(                                   \
                af[mi_][ks_], bfr[ns][ni_][ks_],                                       \
                acc[(ms) * 4 + mi_][(ns) * 2 + ni_], 0, 0, 0);                         \
    PRIO(0);                                                                           \
  } while (0)

__device__ __forceinline__ void run_core(const bf16* __restrict__ Ag,
                                         const bf16* __restrict__ Bg, const int K,
                                         const int bx, const int by, char* smem,
                                         f32x4 (&acc)[8][4]) {
  const int t = threadIdx.x;
  const int w = t >> 6, lane = t & 63;
  const int q = lane >> 4, lr = lane & 15;
  const int wm = w & 1, wn = w >> 1;

  const int r0 = t >> 3;
  const int ksrc = (t & 7) ^ (r0 & 7);
  const bf16* srcA = Ag + (size_t)(by * 256 + r0) * K + ksrc * 8;
  const bf16* srcB = Bg + (size_t)(bx * 256 + r0) * K + ksrc * 8;
  const int wofs = w << 10;

  const int aRow = (wm * 64 + lr) * 128;
  const int bRow = (wn * 32 + lr) * 128;
  const int cb0 = ((q ^ (lr & 7)) << 4);
  const int cb1 = (((4 + q) ^ (lr & 7)) << 4);

#pragma unroll
  for (int i = 0; i < 8; ++i)
#pragma unroll
    for (int j = 0; j < 4; ++j) acc[i][j] = (f32x4){0.f, 0.f, 0.f, 0.f};

  bf16x8 af[4][2];      // current half's A frags
  bf16x8 bfr[2][2][2];  // both n-sub B frags [ns][ni][ks], live across the tile

  // prologue: tile0 (buf0) all 4 units + tile1 (buf1) A0,B0,B1.
  STAGE_A(0, 0, 0); STAGE_B(0, 0, 0); STAGE_B(1, 0, 0); STAGE_A(1, 0, 0);
  STAGE_A(0, 1, 1); STAGE_B(0, 1, 1); STAGE_B(1, 1, 1);
  VMW(6);
  BAR();

  const int NT = K >> 6;  // 64 K-tiles
#pragma unroll 1
  for (int tt = 0; tt + 3 < NT; tt += 2) {
    // ---- tile tt (buf0) ----
    STAGE_A(1, tt + 1, 1);            // buf1.A1: readers retired before prev end-bar
    LDB(0, 0); LDA(0, 0); LDB(1, 0);
    MQ(0, 0); MQ(0, 1);
    BAR();                            // mid: buf0.A0/B0/B1 reads retired
    STAGE_A(0, tt + 2, 0); STAGE_B(0, tt + 2, 0); STAGE_B(1, tt + 2, 0);
    LDA(1, 0);
    MQ(1, 1); MQ(1, 0);
    VMW(6);                           // publish tile tt+1 (drain its 8 loads)
    BAR();
    // ---- tile tt+1 (buf1) ----
    STAGE_A(1, tt + 2, 0);
    LDB(0, 1); LDA(0, 1); LDB(1, 1);
    MQ(0, 0); MQ(0, 1);
    BAR();
    STAGE_A(0, tt + 3, 1); STAGE_B(0, tt + 3, 1); STAGE_B(1, tt + 3, 1);
    LDA(1, 1);
    MQ(1, 1); MQ(1, 0);
    VMW(6);                           // publish tile tt+2
    BAR();
  }

  // peel tile NT-2 (buf0): half2 has no stages; drain everything for tile NT-1
  STAGE_A(1, NT - 1, 1);
  LDB(0, 0); LDA(0, 0); LDB(1, 0);
  MQ(0, 0); MQ(0, 1);
  BAR();
  LDA(1, 0);
  MQ(1, 1); MQ(1, 0);
  VMW(0);
  BAR();
  // peel tile NT-1 (buf1)
  LDB(0, 1); LDA(0, 1); LDB(1, 1);
  MQ(0, 0); MQ(0, 1);
  BAR();
  LDA(1, 1);
  MQ(1, 1); MQ(1, 0);
}

// ---------------------------------------------------------------- GEMM epilogue kernels
// MODE 0: xl0 = A@Wt^T + bias + gate0 ; bf_out ; ssq_out                 [A = xbf]
// MODE 2: xl1 = 2*xl0 - A@G + (gate1-gate0) ; bf_out ; ssq_out          [A = xl0]
// MODE 3: out = xl_prev - A@G + xl0 + (gate2-gate0)  (fp32)             [A = xl1]
template <int MODE>
__global__ __launch_bounds__(512, 2) void k_gemm(
    const bf16* __restrict__ A, const bf16* __restrict__ Bt, int M, int N, int K,
    const float* __restrict__ bias, const bf16* __restrict__ xl0,
    const bf16* __restrict__ xl_prev, float* f32_out, bf16* __restrict__ bf_out,
    const float* __restrict__ ssq_a, const float* __restrict__ ssq_b,
    float* __restrict__ ssq_out) {
  const int nb = gridDim.x * gridDim.y;  // %8==0
  const int lin = blockIdx.y * gridDim.x + blockIdx.x;
  const int sw = (lin & 7) * (nb >> 3) + (lin >> 3);
  const int bx = sw % gridDim.x, by = sw / gridDim.x;
  __shared__ char smem[131072];

  float gate = 0.f;
  if constexpr (MODE == 0) {
    gate = (*ssq_a > 1.0f) ? 0.f : -1.f;
  } else {
    float g0v = (*ssq_a > 1.0f) ? 0.f : -1.f;
    float gtv = (*ssq_b > 1.0f) ? 0.f : -1.f;
    gate = gtv - g0v;
  }
  VMW(0);  // drain gate loads so manual vmcnt counts stay exact

  f32x4 acc[8][4];
  run_core(A, Bt, K, bx, by, smem, acc);

  const int t = threadIdx.x;
  const int w = t >> 6, lane = t & 63;
  const int q = lane >> 4, lr = lane & 15;
  const int wm = w & 1, wn = w >> 1;
  float ssql = 0.f;
#pragma unroll
  for (int mi = 0; mi < 8; ++mi) {
    const int grow = by * 256 + ((mi & 4) ? 128 : 0) + wm * 64 + (mi & 3) * 16 + q * 4;
#pragma unroll
    for (int r = 0; r < 4; ++r) {
      const size_t rowb = (size_t)(grow + r) * N;
#pragma unroll
      for (int ni = 0; ni < 4; ++ni) {
        const int gcol = bx * 256 + ((ni & 2) ? 128 : 0) + wn * 32 + (ni & 1) * 16 + lr;
        const size_t idx = rowb + gcol;
        float v = acc[mi][ni][r];
        if constexpr (MODE == 0) {
          float xl = v + bias[gcol] + gate;
          bf_out[idx] = (bf16)xl;
          ssql += xl * xl;
        } else if constexpr (MODE == 2) {
          float xl = 2.0f * (float)xl0[idx] - v + gate;
          bf_out[idx] = (bf16)xl;
          ssql += xl * xl;
        } else {
          f32_out[idx] = (float)xl_prev[idx] - v + (float)xl0[idx] + gate;
        }
      }
    }
  }
  if constexpr (MODE == 0 || MODE == 2) {
#pragma unroll
    for (int off = 32; off; off >>= 1) ssql += __shfl_down(ssql, off);
    __syncthreads();  // pipeline drained; reuse smem for reduction
    float* red = (float*)smem;
    if (lane == 0) red[w] = ssql;
    __syncthreads();
    if (t == 0) {
      float s = 0.f;
#pragma unroll
      for (int i = 0; i < 8; ++i) s += red[i];
      atomicAdd(ssq_out, s);
    }
  }
}

// ----------------------------------------------------------------
extern "C" void kernel_launch(void* const* d_in, const int* in_sizes, int n_in,
                              void* d_out, int out_size, void* d_ws, size_t ws_size,
                              hipStream_t stream) {
  const float* x = (const float*)d_in[0];
  const float* c0 = (const float*)d_in[1];
  const float* c1 = (const float*)d_in[2];
  const float* c2 = (const float*)d_in[3];
  const float* bias = (const float*)d_in[4];
  float* out = (float*)d_out;

  const int B = 8192, F = 4096;
  char* ws = (char*)d_ws;
  float* scal = (float*)ws;                              // [0]=ssq_x [1]=ssq_xl0 [2]=ssq_xl1
  bf16* xbf = (bf16*)(ws + 256);                         // 64 MiB (x bf16; reused as xl1)
  bf16* Wt = (bf16*)(ws + 256 + (size_t)67108864);       // 32 MiB
  bf16* G = (bf16*)(ws + 256 + (size_t)100663296);       // 32 MiB
  bf16* xl0 = (bf16*)(ws + 256 + (size_t)134217728);     // 64 MiB
  bf16* xl1 = xbf;  // xbf dead after mv GEMM
  float* pbuf = (float*)xl0;  // 4 KB cast partials (xl0 region not yet written)

  // fused pre-work: buildW (4096) | cast+ssq partials (1024)
  k_pre<<<5120, 256, 0, stream>>>(x, c0, c1, c2, Wt, xbf, pbuf);
  // dense G = W^T W fully in-block from TT cores; block 0 finalizes scal[0..2]
  k_buildG<<<256, 256, 0, stream>>>(c0, c1, c2, G, pbuf, scal);

  dim3 g1d(F / 256, B / 256);
  // xl0 = x@W + bias + gate0
  k_gemm<0><<<g1d, 512, 0, stream>>>(xbf, Wt, B, F, F, bias, nullptr, nullptr,
                                     nullptr, xl0, &scal[0], nullptr, &scal[1]);
  // xl1 = 2*xl0 - xl0@G + (gate1-gate0)
  k_gemm<2><<<g1d, 512, 0, stream>>>(xl0, G, B, F, F, nullptr, xl0, nullptr,
                                     nullptr, xl1, &scal[0], &scal[1], &scal[2]);
  // out = xl1 - xl1@G + xl0 + (gate2-gate0)
  k_gemm<3><<<g1d, 512, 0, stream>>>(xl1, G, B, F, F, nullptr, xl0, xl1,
                                     out, nullptr, &scal[0], &scal[2], nullptr);
}

// Round 10
// 941.882 us; speedup vs baseline: 1.1867x; 1.1011x over previous
//
#include <hip/hip_runtime.h>
#include <stdint.h>

typedef __bf16 bf16;
typedef __bf16 bf16x4 __attribute__((ext_vector_type(4)));
typedef __bf16 bf16x8 __attribute__((ext_vector_type(8)));
typedef float f32x4 __attribute__((ext_vector_type(4)));

#define GLD_LDS16(g, l)                                                        \
  __builtin_amdgcn_global_load_lds(                                            \
      (const __attribute__((address_space(1))) void*)(g),                      \
      (__attribute__((address_space(3))) void*)(l), 16, 0, 0)

#define BAR() asm volatile("s_barrier" ::: "memory")
#define VMW(n) asm volatile("s_waitcnt vmcnt(" #n ")" ::: "memory")
#define PRIO(x) __builtin_amdgcn_s_setprio(x)

// ---------------------------------------------------------------- fused pre-work:
// blocks [0,4096): buildW (one output column j each)
// blocks [4096,5120): cast x fp32->bf16 + ||x||^2 partials (no atomic, no init needed)
// blocks [5120,9344): Gram cores g0/g1/g2 of G = W^T W
// Co-scheduling matters: the latency-bound g1 build hides under the HBM-bound cast.
__global__ __launch_bounds__(256) void k_pre(
    const float* __restrict__ x, const float* __restrict__ c0,
    const float* __restrict__ c1, const float* __restrict__ c2,
    bf16* __restrict__ Wt, bf16* __restrict__ xb, float* __restrict__ pbuf,
    float* __restrict__ g0, float* __restrict__ g1, float* __restrict__ g2) {
  const int b = blockIdx.x;
  if (b < 4096) {
    // ---- buildW: Wt[j][*] (bf16, [out=4096][in=4096] row-major) ----
    const int j = b;
    const int j0 = j >> 8, j1 = (j >> 4) & 15, j2 = j & 15;
    const int t = threadIdx.x;
    const int i0 = t >> 4, i1 = t & 15;
    float t0[8];
    {
      float4 v0 = *(const float4*)&c0[(i0 * 16 + j0) * 8];
      float4 v1 = *(const float4*)&c0[(i0 * 16 + j0) * 8 + 4];
      t0[0] = v0.x; t0[1] = v0.y; t0[2] = v0.z; t0[3] = v0.w;
      t0[4] = v1.x; t0[5] = v1.y; t0[6] = v1.z; t0[7] = v1.w;
    }
    float a[8];
#pragma unroll
    for (int r2 = 0; r2 < 8; ++r2) a[r2] = 0.f;
#pragma unroll
    for (int r1 = 0; r1 < 8; ++r1) {
      const float* row = &c1[((r1 * 16 + i1) * 16 + j1) * 8];
      float4 u0 = *(const float4*)row;
      float4 u1 = *(const float4*)(row + 4);
      a[0] += t0[r1] * u0.x; a[1] += t0[r1] * u0.y;
      a[2] += t0[r1] * u0.z; a[3] += t0[r1] * u0.w;
      a[4] += t0[r1] * u1.x; a[5] += t0[r1] * u1.y;
      a[6] += t0[r1] * u1.z; a[7] += t0[r1] * u1.w;
    }
    union { bf16 h[16]; bf16x8 v[2]; } u;
#pragma unroll
    for (int i2 = 0; i2 < 16; ++i2) {
      float s = 0.f;
#pragma unroll
      for (int r2 = 0; r2 < 8; ++r2) s += a[r2] * c2[(r2 * 16 + i2) * 16 + j2];
      u.h[i2] = (bf16)s;
    }
    bf16* dst = Wt + (size_t)j * 4096 + i0 * 256 + i1 * 16;
    ((bf16x8*)dst)[0] = u.v[0];
    ((bf16x8*)dst)[1] = u.v[1];
  } else if (b < 5120) {
    // ---- cast + ssq partial ----
    const int n4 = 8192 * 4096 / 4;
    int tid = (b - 4096) * 256 + threadIdx.x;
    const int stride = 1024 * 256;
    const float4* x4 = (const float4*)x;
    bf16x4* xb4 = (bf16x4*)xb;
    float acc = 0.f;
    for (int i = tid; i < n4; i += stride) {
      float4 v = x4[i];
      acc += v.x * v.x + v.y * v.y + v.z * v.z + v.w * v.w;
      bf16x4 bb;
      bb.x = (bf16)v.x; bb.y = (bf16)v.y; bb.z = (bf16)v.z; bb.w = (bf16)v.w;
      xb4[i] = bb;
    }
#pragma unroll
    for (int off = 32; off; off >>= 1) acc += __shfl_down(acc, off);
    __shared__ float red[4];
    if ((threadIdx.x & 63) == 0) red[threadIdx.x >> 6] = acc;
    __syncthreads();
    if (threadIdx.x == 0) pbuf[b - 4096] = red[0] + red[1] + red[2] + red[3];
  } else {
    // ---- Gram cores ----
    int tid = (b - 5120) * 256 + threadIdx.x;
    if (tid < 16384) {  // g0[(j0,j0')][p1]
      int jj = tid >> 6, p1 = tid & 63;
      int j0 = jj >> 4, j0p = jj & 15, r1 = p1 >> 3, r1p = p1 & 7;
      float s = 0.f;
#pragma unroll
      for (int i0 = 0; i0 < 16; ++i0)
        s += c0[(i0 * 16 + j0) * 8 + r1] * c0[(i0 * 16 + j0p) * 8 + r1p];
      g0[tid] = s;
    } else if (tid < 32768) {  // g2[p2][(j2,j2')]
      int k = tid - 16384;
      int p2 = k >> 8, jj = k & 255;
      int r2 = p2 >> 3, r2p = p2 & 7, j2 = jj >> 4, j2p = jj & 15;
      float s = 0.f;
#pragma unroll
      for (int i2 = 0; i2 < 16; ++i2)
        s += c2[(r2 * 16 + i2) * 16 + j2] * c2[(r2p * 16 + i2) * 16 + j2p];
      g2[k] = s;
    } else {  // g1[p1][(j1,j1')][p2]
      int k = tid - 32768;
      int p2 = k & 63, rest = k >> 6;
      int j1p = rest & 15, j1 = (rest >> 4) & 15, p1 = rest >> 8;
      int r1 = p1 >> 3, r1p = p1 & 7, r2 = p2 >> 3, r2p = p2 & 7;
      float s = 0.f;
#pragma unroll
      for (int i1 = 0; i1 < 16; ++i1)
        s += c1[((r1 * 16 + i1) * 16 + j1) * 8 + r2] *
             c1[((r1p * 16 + i1) * 16 + j1p) * 8 + r2p];
      g1[k] = s;
    }
  }
}

// ---------------------------------------------------------------- dense G from Gram cores
// block 0 additionally reduces the 1024 cast partials -> scal[0], zeroes scal[1..2].
__global__ __launch_bounds__(256) void k_buildG(const float* __restrict__ g0,
                                                const float* __restrict__ g1,
                                                const float* __restrict__ g2,
                                                bf16* __restrict__ G,
                                                const float* __restrict__ pbuf,
                                                float* __restrict__ scal) {
  __shared__ float s_g2[16384];   // [p2][jj2]  64 KB
  __shared__ float s_g1[4096];    // [p1][p2]   16 KB
  __shared__ float s_g0m[16384];  // phase A: g0t [p1][t]; phase B: m_t [p2][jj0]
  const int t = threadIdx.x;

  if (blockIdx.x == 0) {  // ssq finalize (before s_g1 is filled)
    float a = pbuf[t * 4] + pbuf[t * 4 + 1] + pbuf[t * 4 + 2] + pbuf[t * 4 + 3];
#pragma unroll
    for (int off = 32; off; off >>= 1) a += __shfl_down(a, off);
    if ((t & 63) == 0) s_g1[t >> 6] = a;
    __syncthreads();
    if (t == 0) {
      scal[0] = s_g1[0] + s_g1[1] + s_g1[2] + s_g1[3];
      scal[1] = 0.f; scal[2] = 0.f;
    }
    __syncthreads();
  }

  const int j1 = blockIdx.x >> 4, j1p = blockIdx.x & 15;
  const int jj1 = j1 * 16 + j1p;

  const float4* g2f4 = (const float4*)g2;
  float4* sg2f4 = (float4*)s_g2;
  for (int k = t; k < 4096; k += 256) sg2f4[k] = g2f4[k];
  const float4* g1f4 = (const float4*)g1;
  float4* sg1f4 = (float4*)s_g1;
  for (int k = t; k < 1024; k += 256) {
    int p1 = k >> 4, q = k & 15;
    sg1f4[k] = g1f4[(p1 * 256 + jj1) * 16 + q];
  }
#pragma unroll
  for (int q = 0; q < 16; ++q) {
    float4 v = ((const float4*)g0)[t * 16 + q];
    s_g0m[(q * 4 + 0) * 256 + t] = v.x;
    s_g0m[(q * 4 + 1) * 256 + t] = v.y;
    s_g0m[(q * 4 + 2) * 256 + t] = v.z;
    s_g0m[(q * 4 + 3) * 256 + t] = v.w;
  }
  __syncthreads();

  // stage 1: m[p2] for jj0 = t
  float m[64];
#pragma unroll
  for (int i = 0; i < 64; ++i) m[i] = 0.f;
#pragma unroll 4
  for (int p1 = 0; p1 < 64; ++p1) {
    float av = s_g0m[p1 * 256 + t];
#pragma unroll
    for (int q = 0; q < 16; ++q) {
      float4 v = ((const float4*)s_g1)[p1 * 16 + q];
      m[q * 4 + 0] += av * v.x; m[q * 4 + 1] += av * v.y;
      m[q * 4 + 2] += av * v.z; m[q * 4 + 3] += av * v.w;
    }
  }
  __syncthreads();
#pragma unroll
  for (int p2 = 0; p2 < 64; ++p2) s_g0m[p2 * 256 + t] = m[p2];  // m_t[p2][jj0]
  __syncthreads();

  // stage 2: thread t -> jj2 tile (t&15)*16, jj0 tiles ((t>>4)+rep*16)*8
  const int bcol = (t & 15) * 16;
  const int j2 = t & 15;
#pragma unroll 1
  for (int rep = 0; rep < 2; ++rep) {
    const int r0 = (((t >> 4) + rep * 16)) * 8;
    float acc2[8][16];
#pragma unroll
    for (int i = 0; i < 8; ++i)
#pragma unroll
      for (int c = 0; c < 16; ++c) acc2[i][c] = 0.f;
#pragma unroll 2
    for (int p2 = 0; p2 < 64; ++p2) {
      float4 mv0 = *(const float4*)&s_g0m[p2 * 256 + r0];
      float4 mv1 = *(const float4*)&s_g0m[p2 * 256 + r0 + 4];
      float mv[8] = {mv0.x, mv0.y, mv0.z, mv0.w, mv1.x, mv1.y, mv1.z, mv1.w};
      float gv[16];
#pragma unroll
      for (int q = 0; q < 4; ++q) {
        float4 v = *(const float4*)&s_g2[p2 * 256 + bcol + q * 4];
        gv[q * 4 + 0] = v.x; gv[q * 4 + 1] = v.y;
        gv[q * 4 + 2] = v.z; gv[q * 4 + 3] = v.w;
      }
#pragma unroll
      for (int i = 0; i < 8; ++i)
#pragma unroll
        for (int c = 0; c < 16; ++c) acc2[i][c] += mv[i] * gv[c];
    }
#pragma unroll
    for (int i = 0; i < 8; ++i) {
      const int jj0 = r0 + i;
      const int j0 = jj0 >> 4, j0p = jj0 & 15;
      bf16* d = G + (size_t)(j0 * 256 + j1 * 16 + j2) * 4096 + (j0p * 256 + j1p * 16);
      union { bf16 h[16]; bf16x8 v[2]; } u;
#pragma unroll
      for (int c = 0; c < 16; ++c) u.h[c] = (bf16)acc2[i][c];
      ((bf16x8*)d)[0] = u.v[0];
      ((bf16x8*)d)[1] = u.v[1];
    }
  }
}

// ---------------------------------------------------------------- 256x256 BT-form GEMM core
// (verified best core: ~251us, 0 bank conflicts)
// C[m,n] = sum_k A[m,k]*Bt[n,k].  BM=BN=256, BK=64, 512 thr = 8 waves (2M x 4N).
// 2 barriers per K-tile (mid + end); compiler-counted lgkmcnt paces each wave's
// reads->MFMA. vmcnt(6) publish keeps next tile's loads in flight, never drains.
// LDS chunk swizzle: slot (row,c) holds global chunk c ^ (row&7) (pre-swizzled source).
#define STAGE_A(h, kt, b)                                                              \
  do {                                                                                 \
    GLD_LDS16(srcA + (size_t)((h) * 128) * K + (kt) * 64,                              \
              smem + (b) * 65536 + (h) * 16384 + wofs);                                \
    GLD_LDS16(srcA + (size_t)((h) * 128 + 64) * K + (kt) * 64,                         \
              smem + (b) * 65536 + (h) * 16384 + 8192 + wofs);                         \
  } while (0)
#define STAGE_B(h, kt, b)                                                              \
  do {                                                                                 \
    GLD_LDS16(srcB + (size_t)((h) * 128) * K + (kt) * 64,                              \
              smem + (b) * 65536 + 32768 + (h) * 16384 + wofs);                        \
    GLD_LDS16(srcB + (size_t)((h) * 128 + 64) * K + (kt) * 64,                         \
              smem + (b) * 65536 + 32768 + (h) * 16384 + 8192 + wofs);                 \
  } while (0)
#define LDA(ms, b)                                                                     \
  do {                                                                                 \
    const char* s_ = smem + (b) * 65536 + (ms) * 16384 + aRow;                         \
    _Pragma("unroll") for (int mi_ = 0; mi_ < 4; ++mi_) {                              \
      af[mi_][0] = *(const bf16x8*)(s_ + mi_ * 2048 + cb0);                            \
      af[mi_][1] = *(const bf16x8*)(s_ + mi_ * 2048 + cb1);                            \
    }                                                                                  \
  } while (0)
#define LDB(ns, b)                                                                     \
  do {                                                                                 \
    const char* s_ = smem + (b) * 65536 + 32768 + (ns) * 16384 + bRow;                 \
    _Pragma("unroll") for (int ni_ = 0; ni_ < 2; ++ni_) {                              \
      bfr[ns][ni_][0] = *(const bf16x8*)(s_ + ni_ * 2048 + cb0);                       \
      bfr[ns][ni_][1] = *(const bf16x8*)(s_ + ni_ * 2048 + cb1);                       \
    }                                                                                  \
  } while (0)
#define MQ(ms, ns)                                                                     \
  do {                                                                                 \
    PRIO(1);                                                                           \
    _Pragma("unroll") for (int mi_ = 0; mi_ < 4; ++mi_)                                \
    _Pragma("unroll") for (int ni_ = 0; ni_ < 2; ++ni_)                                \
    _Pragma("unroll") for (int ks_ = 0; ks_ < 2; ++ks_)                                \
        acc[(ms) * 4 + mi_][(ns) * 2 + ni_] =                                          \
            __builtin_amdgcn_mfma_f32_16x16x32_bf16(                                   \
                af[mi_][ks_], bfr[ns][ni_][ks_],                                       \
                acc[(ms) * 4 + mi_][(ns) * 2 + ni_], 0, 0, 0);                         \
    PRIO(0);                                                                           \
  } while (0)

__device__ __forceinline__ void run_core(const bf16* __restrict__ Ag,
                                         const bf16* __restrict__ Bg, const int K,
                                         const int bx, const int by, char* smem,
                                         f32x4 (&acc)[8][4]) {
  const int t = threadIdx.x;
  const int w = t >> 6, lane = t & 63;
  const int q = lane >> 4, lr = lane & 15;
  const int wm = w & 1, wn = w >> 1;

  const int r0 = t >> 3;
  const int ksrc = (t & 7) ^ (r0 & 7);
  const bf16* srcA = Ag + (size_t)(by * 256 + r0) * K + ksrc * 8;
  const bf16* srcB = Bg + (size_t)(bx * 256 + r0) * K + ksrc * 8;
  const int wofs = w << 10;

  const int aRow = (wm * 64 + lr) * 128;
  const int bRow = (wn * 32 + lr) * 128;
  const int cb0 = ((q ^ (lr & 7)) << 4);
  const int cb1 = (((4 + q) ^ (lr & 7)) << 4);

#pragma unroll
  for (int i = 0; i < 8; ++i)
#pragma unroll
    for (int j = 0; j < 4; ++j) acc[i][j] = (f32x4){0.f, 0.f, 0.f, 0.f};

  bf16x8 af[4][2];      // current half's A frags
  bf16x8 bfr[2][2][2];  // both n-sub B frags [ns][ni][ks], live across the tile

  // prologue: tile0 (buf0) all 4 units + tile1 (buf1) A0,B0,B1.
  STAGE_A(0, 0, 0); STAGE_B(0, 0, 0); STAGE_B(1, 0, 0); STAGE_A(1, 0, 0);
  STAGE_A(0, 1, 1); STAGE_B(0, 1, 1); STAGE_B(1, 1, 1);
  VMW(6);
  BAR();

  const int NT = K >> 6;  // 64 K-tiles
#pragma unroll 1
  for (int tt = 0; tt + 3 < NT; tt += 2) {
    // ---- tile tt (buf0) ----
    STAGE_A(1, tt + 1, 1);            // buf1.A1: readers retired before prev end-bar
    LDB(0, 0); LDA(0, 0); LDB(1, 0);
    MQ(0, 0); MQ(0, 1);
    BAR();                            // mid: buf0.A0/B0/B1 reads retired
    STAGE_A(0, tt + 2, 0); STAGE_B(0, tt + 2, 0); STAGE_B(1, tt + 2, 0);
    LDA(1, 0);
    MQ(1, 1); MQ(1, 0);
    VMW(6);                           // publish tile tt+1 (drain its 8 loads)
    BAR();
    // ---- tile tt+1 (buf1) ----
    STAGE_A(1, tt + 2, 0);
    LDB(0, 1); LDA(0, 1); LDB(1, 1);
    MQ(0, 0); MQ(0, 1);
    BAR();
    STAGE_A(0, tt + 3, 1); STAGE_B(0, tt + 3, 1); STAGE_B(1, tt + 3, 1);
    LDA(1, 1);
    MQ(1, 1); MQ(1, 0);
    VMW(6);                           // publish tile tt+2
    BAR();
  }

  // peel tile NT-2 (buf0): half2 has no stages; drain everything for tile NT-1
  STAGE_A(1, NT - 1, 1);
  LDB(0, 0); LDA(0, 0); LDB(1, 0);
  MQ(0, 0); MQ(0, 1);
  BAR();
  LDA(1, 0);
  MQ(1, 1); MQ(1, 0);
  VMW(0);
  BAR();
  // peel tile NT-1 (buf1)
  LDB(0, 1); LDA(0, 1); LDB(1, 1);
  MQ(0, 0); MQ(0, 1);
  BAR();
  LDA(1, 1);
  MQ(1, 1); MQ(1, 0);
}

// ---------------------------------------------------------------- GEMM epilogue kernels
// MODE 0: xl0 = A@Wt^T + bias + gate0 ; bf_out ; ssq_out                 [A = xbf]
// MODE 2: xl1 = 2*xl0 - A@G + (gate1-gate0) ; bf_out ; ssq_out          [A = xl0]
// MODE 3: out = xl_prev - A@G + xl0 + (gate2-gate0)  (fp32)             [A = xl1]
template <int MODE>
__global__ __launch_bounds__(512, 2) void k_gemm(
    const bf16* __restrict__ A, const bf16* __restrict__ Bt, int M, int N, int K,
    const float* __restrict__ bias, const bf16* __restrict__ xl0,
    const bf16* __restrict__ xl_prev, float* f32_out, bf16* __restrict__ bf_out,
    const float* __restrict__ ssq_a, const float* __restrict__ ssq_b,
    float* __restrict__ ssq_out) {
  const int nb = gridDim.x * gridDim.y;  // %8==0
  const int lin = blockIdx.y * gridDim.x + blockIdx.x;
  const int sw = (lin & 7) * (nb >> 3) + (lin >> 3);
  const int bx = sw % gridDim.x, by = sw / gridDim.x;
  __shared__ char smem[131072];

  float gate = 0.f;
  if constexpr (MODE == 0) {
    gate = (*ssq_a > 1.0f) ? 0.f : -1.f;
  } else {
    float g0v = (*ssq_a > 1.0f) ? 0.f : -1.f;
    float gtv = (*ssq_b > 1.0f) ? 0.f : -1.f;
    gate = gtv - g0v;
  }
  VMW(0);  // drain gate loads so manual vmcnt counts stay exact

  f32x4 acc[8][4];
  run_core(A, Bt, K, bx, by, smem, acc);

  const int t = threadIdx.x;
  const int w = t >> 6, lane = t & 63;
  const int q = lane >> 4, lr = lane & 15;
  const int wm = w & 1, wn = w >> 1;
  float ssql = 0.f;
#pragma unroll
  for (int mi = 0; mi < 8; ++mi) {
    const int grow = by * 256 + ((mi & 4) ? 128 : 0) + wm * 64 + (mi & 3) * 16 + q * 4;
#pragma unroll
    for (int r = 0; r < 4; ++r) {
      const size_t rowb = (size_t)(grow + r) * N;
#pragma unroll
      for (int ni = 0; ni < 4; ++ni) {
        const int gcol = bx * 256 + ((ni & 2) ? 128 : 0) + wn * 32 + (ni & 1) * 16 + lr;
        const size_t idx = rowb + gcol;
        float v = acc[mi][ni][r];
        if constexpr (MODE == 0) {
          float xl = v + bias[gcol] + gate;
          bf_out[idx] = (bf16)xl;
          ssql += xl * xl;
        } else if constexpr (MODE == 2) {
          float xl = 2.0f * (float)xl0[idx] - v + gate;
          bf_out[idx] = (bf16)xl;
          ssql += xl * xl;
        } else {
          f32_out[idx] = (float)xl_prev[idx] - v + (float)xl0[idx] + gate;
        }
      }
    }
  }
  if constexpr (MODE == 0 || MODE == 2) {
#pragma unroll
    for (int off = 32; off; off >>= 1) ssql += __shfl_down(ssql, off);
    __syncthreads();  // pipeline drained; reuse smem for reduction
    float* red = (float*)smem;
    if (lane == 0) red[w] = ssql;
    __syncthreads();
    if (t == 0) {
      float s = 0.f;
#pragma unroll
      for (int i = 0; i < 8; ++i) s += red[i];
      atomicAdd(ssq_out, s);
    }
  }
}

// ----------------------------------------------------------------
extern "C" void kernel_launch(void* const* d_in, const int* in_sizes, int n_in,
                              void* d_out, int out_size, void* d_ws, size_t ws_size,
                              hipStream_t stream) {
  const float* x = (const float*)d_in[0];
  const float* c0 = (const float*)d_in[1];
  const float* c1 = (const float*)d_in[2];
  const float* c2 = (const float*)d_in[3];
  const float* bias = (const float*)d_in[4];
  float* out = (float*)d_out;

  const int B = 8192, F = 4096;
  char* ws = (char*)d_ws;
  float* scal = (float*)ws;                              // [0]=ssq_x [1]=ssq_xl0 [2]=ssq_xl1
  bf16* xbf = (bf16*)(ws + 256);                         // 64 MiB (x bf16; reused as xl1)
  bf16* Wt = (bf16*)(ws + 256 + (size_t)67108864);       // 32 MiB
  bf16* G = (bf16*)(ws + 256 + (size_t)100663296);       // 32 MiB
  bf16* xl0 = (bf16*)(ws + 256 + (size_t)134217728);     // 64 MiB
  bf16* xl1 = xbf;  // xbf dead after mv GEMM
  // Gram-core scratch + cast partials live in the (not-yet-written) xl0 region.
  float* g0 = (float*)xl0;           // 64 KB
  float* g2 = g0 + 16384;            // 64 KB
  float* g1 = g2 + 16384;            // 4 MiB
  float* pbuf = g1 + 1048576;        // 4 KB (1024 cast partials)

  // fused pre-work: buildW (4096) | cast+ssq partials (1024) | Gram cores (4224)
  k_pre<<<9344, 256, 0, stream>>>(x, c0, c1, c2, Wt, xbf, pbuf, g0, g1, g2);
  // dense G from Gram cores; block 0 finalizes scal[0..2]
  k_buildG<<<256, 256, 0, stream>>>(g0, g1, g2, G, pbuf, scal);

  dim3 g1d(F / 256, B / 256);
  // xl0 = x@W + bias + gate0
  k_gemm<0><<<g1d, 512, 0, stream>>>(xbf, Wt, B, F, F, bias, nullptr, nullptr,
                                     nullptr, xl0, &scal[0], nullptr, &scal[1]);
  // xl1 = 2*xl0 - xl0@G + (gate1-gate0)
  k_gemm<2><<<g1d, 512, 0, stream>>>(xl0, G, B, F, F, nullptr, xl0, nullptr,
                                     nullptr, xl1, &scal[0], &scal[1], &scal[2]);
  // out = xl1 - xl1@G + xl0 + (gate2-gate0)
  k_gemm<3><<<g1d, 512, 0, stream>>>(xl1, G, B, F, F, nullptr, xl0, xl1,
                                     out, nullptr, &scal[0], &scal[2], nullptr);
}